// Round 2
// baseline (221.294 us; speedup 1.0000x reference)
//
#include <hip/hip_runtime.h>
#include <math.h>

#define C_IN   256
#define C_HEAD 32
#define HW     361          // 19*19
#define NTHR   384          // 6 waves
#define CV     48
#define B_PER  2            // batch elements per block

__global__ __launch_bounds__(NTHR) void vh_fused(
    const float* __restrict__ x,
    const float* __restrict__ conv_w,
    const float* __restrict__ fc1_w, const float* __restrict__ fc1_b,
    const float* __restrict__ fc2_w, const float* __restrict__ fc2_b,
    const float* __restrict__ fc3_w, const float* __restrict__ fc3_b,
    const float* __restrict__ sc_w,  const float* __restrict__ sc_b,
    const float* __restrict__ fc4_w, const float* __restrict__ fc4_b,
    const float* __restrict__ fc5_w, const float* __restrict__ fc5_b,
    float* __restrict__ out, int B)
{
    const int b0   = blockIdx.x * B_PER;
    const int tid  = threadIdx.x;
    const int wave = tid >> 6;
    const int lane = tid & 63;
    const int p    = tid;
    const bool act = (p < HW);
    const int pc   = act ? p : (HW - 1);   // clamp: loop stays convergent, weight addrs uniform

    __shared__ float lds_sum[B_PER][C_HEAD][6];
    __shared__ float lds_max[B_PER][C_HEAD][6];
    __shared__ float vp[B_PER][3 * C_HEAD];
    __shared__ float base_l[B_PER][CV], dco_l[B_PER][CV], f5_l[B_PER][CV];

    float acc[B_PER][C_HEAD];
    #pragma unroll
    for (int bb = 0; bb < B_PER; ++bb)
        #pragma unroll
        for (int o = 0; o < C_HEAD; ++o) acc[bb][o] = 0.f;

    const float* __restrict__ xb = x + (size_t)b0 * C_IN * HW;

    // ---- 1x1 conv: V[b,o,p] = sum_c x[b,c,p] * w[o,c], two batch streams ----
    #pragma unroll 8
    for (int c = 0; c < C_IN; ++c) {
        float xv0 = xb[c * HW + pc];
        float xv1 = xb[C_IN * HW + c * HW + pc];
        #pragma unroll
        for (int o = 0; o < C_HEAD; ++o) {
            float w = conv_w[o * C_IN + c];
            acc[0][o] = fmaf(xv0, w, acc[0][o]);
            acc[1][o] = fmaf(xv1, w, acc[1][o]);
        }
    }

    // ---- spatial mean & max reduction (per wave, then cross-wave via LDS) ----
    #pragma unroll
    for (int bb = 0; bb < B_PER; ++bb) {
        #pragma unroll
        for (int o = 0; o < C_HEAD; ++o) {
            float s = act ? acc[bb][o] : 0.f;
            float m = act ? acc[bb][o] : -3.0e38f;
            #pragma unroll
            for (int off = 32; off > 0; off >>= 1) {
                s += __shfl_xor(s, off, 64);
                m  = fmaxf(m, __shfl_xor(m, off, 64));
            }
            if (lane == 0) { lds_sum[bb][o][wave] = s; lds_max[bb][o][wave] = m; }
        }
    }
    __syncthreads();

    if (tid < B_PER * C_HEAD) {
        const int bb = tid >> 5;
        const int o  = tid & 31;
        float s = 0.f, m = -3.0e38f;
        #pragma unroll
        for (int w = 0; w < 6; ++w) { s += lds_sum[bb][o][w]; m = fmaxf(m, lds_max[bb][o][w]); }
        float mean1 = s * (1.0f / (float)HW);
        vp[bb][o]              = mean1;
        vp[bb][C_HEAD + o]     = mean1 * ((19.0f - 9.0f) * 0.1f);
        vp[bb][2 * C_HEAD + o] = m;
    }
    __syncthreads();

    // ---- heads: wave 0 -> batch b0, wave 1 -> batch b0+1 ----
    if (wave < B_PER) {
        const int bb = wave;
        const int b  = b0 + bb;
        const int j  = lane;
        float h1 = 0.f, h3 = 0.f;
        if (j < CV) {
            float a1 = fc1_b[j], a3 = fc3_b[j], a4 = fc4_b[j];
            #pragma unroll
            for (int k = 0; k < 96; ++k) {
                float v = vp[bb][k];
                a1 = fmaf(v, fc1_w[j * 96 + k], a1);
                a3 = fmaf(v, fc3_w[j * 96 + k], a3);
                a4 = fmaf(v, fc4_w[j * 97 + k], a4);
            }
            h1 = fmaxf(a1, 0.f) * fc2_w[j];
            h3 = fmaxf(a3, 0.f) * sc_w[j];
            base_l[bb][j] = a4;
            dco_l[bb][j]  = fc4_w[j * 97 + 96];
            f5_l[bb][j]   = fc5_w[j];
        }
        // game outcome + scaling (48-lane dot reductions)
        float s1 = h1, s3 = h3;
        #pragma unroll
        for (int off = 32; off > 0; off >>= 1) {
            s1 += __shfl_xor(s1, off, 64);
            s3 += __shfl_xor(s3, off, 64);
        }
        float game = tanhf(s1 + fc2_b[0]);
        float scal = s3 + sc_b[0];
        if (lane == 0) out[b] = game;

        // distance logits: lane d in [0,41)
        float z = -3.0e38f;
        if (lane < 41) {
            float dval = (float)(lane - 20);
            float lg = fc5_b[0];
            #pragma unroll
            for (int jj = 0; jj < CV; ++jj) {
                float t = fmaf(dval, dco_l[bb][jj], base_l[bb][jj]);
                t = fmaxf(t, 0.f);
                lg = fmaf(t, f5_l[bb][jj], lg);
            }
            z = lg * scal;
        }
        // softmax over 41 lanes
        float mz = z;
        #pragma unroll
        for (int off = 32; off > 0; off >>= 1) mz = fmaxf(mz, __shfl_xor(mz, off, 64));
        float e = (lane < 41) ? expf(z - mz) : 0.f;
        float se = e;
        #pragma unroll
        for (int off = 32; off > 0; off >>= 1) se += __shfl_xor(se, off, 64);
        if (lane < 41) out[B + b * 41 + lane] = e / se;
    }
}

extern "C" void kernel_launch(void* const* d_in, const int* in_sizes, int n_in,
                              void* d_out, int out_size, void* d_ws, size_t ws_size,
                              hipStream_t stream) {
    const float* x      = (const float*)d_in[0];
    const float* conv_w = (const float*)d_in[1];
    const float* fc1_w  = (const float*)d_in[2];
    const float* fc1_b  = (const float*)d_in[3];
    const float* fc2_w  = (const float*)d_in[4];
    const float* fc2_b  = (const float*)d_in[5];
    const float* fc3_w  = (const float*)d_in[6];
    const float* fc3_b  = (const float*)d_in[7];
    const float* sc_w   = (const float*)d_in[8];
    const float* sc_b   = (const float*)d_in[9];
    const float* fc4_w  = (const float*)d_in[10];
    const float* fc4_b  = (const float*)d_in[11];
    const float* fc5_w  = (const float*)d_in[12];
    const float* fc5_b  = (const float*)d_in[13];
    float* out = (float*)d_out;

    int B = in_sizes[0] / (C_IN * HW);

    vh_fused<<<dim3(B / B_PER), dim3(NTHR), 0, stream>>>(
        x, conv_w, fc1_w, fc1_b, fc2_w, fc2_b, fc3_w, fc3_b,
        sc_w, sc_b, fc4_w, fc4_b, fc5_w, fc5_b, out, B);
}

// Round 3
// 143.371 us; speedup vs baseline: 1.5435x; 1.5435x over previous
//
#include <hip/hip_runtime.h>
#include <math.h>

#define C_IN   256
#define C_HEAD 32
#define HW     361          // 19*19
#define NTHR   384          // 6 waves
#define CV     48
#define KC     64           // K-chunk (c's per LDS tile)
#define XSTR   72           // LDS row stride in bf16 (64 + 8 pad -> 144B = 16*9, 2-way banks)

typedef __attribute__((ext_vector_type(8))) short bf16x8;
typedef __attribute__((ext_vector_type(4))) float f32x4;

static __device__ __forceinline__ unsigned short f2bf(float f) {
    unsigned int u = __builtin_bit_cast(unsigned int, f);
    u += 0x7fffu + ((u >> 16) & 1u);          // RNE
    return (unsigned short)(u >> 16);
}

__global__ __launch_bounds__(NTHR) void vh_fused(
    const float* __restrict__ x,
    const float* __restrict__ conv_w,
    const float* __restrict__ fc1_w, const float* __restrict__ fc1_b,
    const float* __restrict__ fc2_w, const float* __restrict__ fc2_b,
    const float* __restrict__ fc3_w, const float* __restrict__ fc3_b,
    const float* __restrict__ sc_w,  const float* __restrict__ sc_b,
    const float* __restrict__ fc4_w, const float* __restrict__ fc4_b,
    const float* __restrict__ fc5_w, const float* __restrict__ fc5_b,
    float* __restrict__ out, int B)
{
    const int b    = blockIdx.x;
    const int tid  = threadIdx.x;
    const int wave = tid >> 6;
    const int lane = tid & 63;
    const int l15  = lane & 15;
    const int g    = lane >> 4;
    const int p    = tid;
    const int pc   = (p < HW) ? p : (HW - 1);

    __shared__ __align__(16) unsigned short xt[NTHR * XSTR];   // X tile [p][c] bf16, 55.3 KB
    __shared__ __align__(16) unsigned short wt[C_IN * C_HEAD]; // W^T [c][o] bf16, 16 KB
    __shared__ float lds_psum[C_HEAD][6];
    __shared__ float lds_pmax[C_HEAD][6];
    __shared__ float vp[3 * C_HEAD];
    __shared__ float base_l[CV], dco_l[CV], f5_l[CV];

    // ---- build W^T in LDS (one-time): wt[c*32+o] = bf16(conv_w[o*256+c]) ----
    for (int i = tid; i < C_IN * C_HEAD; i += NTHR) {
        float wv = conv_w[(i & 31) * C_IN + (i >> 5)];
        wt[i] = f2bf(wv);
    }
    __syncthreads();

    // ---- load W^T MFMA B-fragments into registers (held all kernel) ----
    // B[k][n]: lane holds k = K0*32 + g*8 + e, col = n*16 + l15
    bf16x8 wfrag[8][2];
    #pragma unroll
    for (int K0 = 0; K0 < 8; ++K0) {
        #pragma unroll
        for (int n = 0; n < 2; ++n) {
            bf16x8 f;
            #pragma unroll
            for (int e = 0; e < 8; ++e) {
                int k = K0 * 32 + g * 8 + e;
                f[e] = (short)wt[k * C_HEAD + n * 16 + l15];
            }
            wfrag[K0][n] = f;
        }
    }

    f32x4 acc[4][2];
    #pragma unroll
    for (int mi = 0; mi < 4; ++mi)
        #pragma unroll
        for (int n = 0; n < 2; ++n)
            acc[mi][n] = (f32x4){0.f, 0.f, 0.f, 0.f};

    const float* __restrict__ xb = x + (size_t)b * C_IN * HW + pc;

    // ---- K-chunks: stage x[c0..c0+63][p] as bf16 into xt[p][c], then MFMA ----
    #pragma unroll
    for (int q = 0; q < 4; ++q) {
        const float* xc = xb + q * KC * HW;
        #pragma unroll
        for (int j = 0; j < 8; ++j) {          // 8 c's per b128 write
            float v[8];
            #pragma unroll
            for (int i = 0; i < 8; ++i) v[i] = xc[(j * 8 + i) * HW];
            unsigned int pk[4];
            #pragma unroll
            for (int i = 0; i < 4; ++i)
                pk[i] = (unsigned int)f2bf(v[2 * i]) | ((unsigned int)f2bf(v[2 * i + 1]) << 16);
            *(uint4*)&xt[p * XSTR + j * 8] = make_uint4(pk[0], pk[1], pk[2], pk[3]);
        }
        __syncthreads();

        // compute: A = X rows (p), k-contiguous b128 reads
        #pragma unroll
        for (int kk = 0; kk < 2; ++kk) {
            #pragma unroll
            for (int mi = 0; mi < 4; ++mi) {
                const int row = wave * 64 + mi * 16 + l15;
                bf16x8 a = *(const bf16x8*)&xt[row * XSTR + kk * 32 + g * 8];
                #pragma unroll
                for (int n = 0; n < 2; ++n)
                    acc[mi][n] = __builtin_amdgcn_mfma_f32_16x16x32_bf16(
                        a, wfrag[q * 2 + kk][n], acc[mi][n], 0, 0, 0);
            }
        }
        __syncthreads();
    }

    // ---- reduce over positions: lane holds D[p = wave*64+mi*16+g*4+r][o = n*16+l15] ----
    float s[2]  = {0.f, 0.f};
    float mx[2] = {-3.0e38f, -3.0e38f};
    #pragma unroll
    for (int n = 0; n < 2; ++n) {
        #pragma unroll
        for (int mi = 0; mi < 4; ++mi) {
            #pragma unroll
            for (int r = 0; r < 4; ++r) {
                int pp = wave * 64 + mi * 16 + g * 4 + r;
                float v = acc[mi][n][r];
                if (pp < HW) { s[n] += v; mx[n] = fmaxf(mx[n], v); }
            }
        }
        s[n] += __shfl_xor(s[n], 16, 64);
        s[n] += __shfl_xor(s[n], 32, 64);
        mx[n] = fmaxf(mx[n], __shfl_xor(mx[n], 16, 64));
        mx[n] = fmaxf(mx[n], __shfl_xor(mx[n], 32, 64));
    }
    if (lane < 32) {
        lds_psum[lane][wave] = (lane < 16) ? s[0] : s[1];
        lds_pmax[lane][wave] = (lane < 16) ? mx[0] : mx[1];
    }
    __syncthreads();

    if (tid < C_HEAD) {
        float ss = 0.f, mm = -3.0e38f;
        #pragma unroll
        for (int w = 0; w < 6; ++w) { ss += lds_psum[tid][w]; mm = fmaxf(mm, lds_pmax[tid][w]); }
        float mean1 = ss * (1.0f / (float)HW);
        vp[tid]              = mean1;
        vp[C_HEAD + tid]     = mean1 * ((19.0f - 9.0f) * 0.1f);
        vp[2 * C_HEAD + tid] = mm;
    }
    __syncthreads();

    // ---- heads: wave 0 ----
    if (wave == 0) {
        const int j = lane;
        float h1 = 0.f, h3 = 0.f;
        if (j < CV) {
            float a1 = fc1_b[j], a3 = fc3_b[j], a4 = fc4_b[j];
            #pragma unroll
            for (int k = 0; k < 96; ++k) {
                float v = vp[k];
                a1 = fmaf(v, fc1_w[j * 96 + k], a1);
                a3 = fmaf(v, fc3_w[j * 96 + k], a3);
                a4 = fmaf(v, fc4_w[j * 97 + k], a4);
            }
            h1 = fmaxf(a1, 0.f) * fc2_w[j];
            h3 = fmaxf(a3, 0.f) * sc_w[j];
            base_l[j] = a4;
            dco_l[j]  = fc4_w[j * 97 + 96];
            f5_l[j]   = fc5_w[j];
        }
        float s1 = h1, s3 = h3;
        #pragma unroll
        for (int off = 32; off > 0; off >>= 1) {
            s1 += __shfl_xor(s1, off, 64);
            s3 += __shfl_xor(s3, off, 64);
        }
        float game = tanhf(s1 + fc2_b[0]);
        float scal = s3 + sc_b[0];
        if (lane == 0) out[b] = game;

        float z = -3.0e38f;
        if (lane < 41) {
            float dval = (float)(lane - 20);
            float lg = fc5_b[0];
            #pragma unroll
            for (int jj = 0; jj < CV; ++jj) {
                float t = fmaf(dval, dco_l[jj], base_l[jj]);
                t = fmaxf(t, 0.f);
                lg = fmaf(t, f5_l[jj], lg);
            }
            z = lg * scal;
        }
        float mz = z;
        #pragma unroll
        for (int off = 32; off > 0; off >>= 1) mz = fmaxf(mz, __shfl_xor(mz, off, 64));
        float e = (lane < 41) ? expf(z - mz) : 0.f;
        float se = e;
        #pragma unroll
        for (int off = 32; off > 0; off >>= 1) se += __shfl_xor(se, off, 64);
        if (lane < 41) out[B + b * 41 + lane] = e / se;
    }
}

extern "C" void kernel_launch(void* const* d_in, const int* in_sizes, int n_in,
                              void* d_out, int out_size, void* d_ws, size_t ws_size,
                              hipStream_t stream) {
    const float* x      = (const float*)d_in[0];
    const float* conv_w = (const float*)d_in[1];
    const float* fc1_w  = (const float*)d_in[2];
    const float* fc1_b  = (const float*)d_in[3];
    const float* fc2_w  = (const float*)d_in[4];
    const float* fc2_b  = (const float*)d_in[5];
    const float* fc3_w  = (const float*)d_in[6];
    const float* fc3_b  = (const float*)d_in[7];
    const float* sc_w   = (const float*)d_in[8];
    const float* sc_b   = (const float*)d_in[9];
    const float* fc4_w  = (const float*)d_in[10];
    const float* fc4_b  = (const float*)d_in[11];
    const float* fc5_w  = (const float*)d_in[12];
    const float* fc5_b  = (const float*)d_in[13];
    float* out = (float*)d_out;

    int B = in_sizes[0] / (C_IN * HW);

    vh_fused<<<dim3(B), dim3(NTHR), 0, stream>>>(
        x, conv_w, fc1_w, fc1_b, fc2_w, fc2_b, fc3_w, fc3_b,
        sc_w, sc_b, fc4_w, fc4_b, fc5_w, fc5_b, out, B);
}

// Round 4
// 111.635 us; speedup vs baseline: 1.9823x; 1.2843x over previous
//
#include <hip/hip_runtime.h>
#include <math.h>

#define C_IN   256
#define C_HEAD 32
#define HW     361          // 19*19
#define NTHR   384          // 6 waves
#define CV     48
#define WSTR   264          // wtT row stride in bf16 (256+8 pad): 528B = 132 dwords, 4-bank row shift

typedef __attribute__((ext_vector_type(8))) short bf16x8;
typedef __attribute__((ext_vector_type(4))) float f32x4;

static __device__ __forceinline__ unsigned short f2bf(float f) {
    unsigned int u = __builtin_bit_cast(unsigned int, f);
    u += 0x7fffu + ((u >> 16) & 1u);          // RNE
    return (unsigned short)(u >> 16);
}

__global__ __launch_bounds__(NTHR, 4) void vh_fused(
    const float* __restrict__ x,
    const float* __restrict__ conv_w,
    const float* __restrict__ fc1_w, const float* __restrict__ fc1_b,
    const float* __restrict__ fc2_w, const float* __restrict__ fc2_b,
    const float* __restrict__ fc3_w, const float* __restrict__ fc3_b,
    const float* __restrict__ sc_w,  const float* __restrict__ sc_b,
    const float* __restrict__ fc4_w, const float* __restrict__ fc4_b,
    const float* __restrict__ fc5_w, const float* __restrict__ fc5_b,
    float* __restrict__ out, int B)
{
    const int b    = blockIdx.x;
    const int tid  = threadIdx.x;
    const int wave = tid >> 6;
    const int lane = tid & 63;
    const int l15  = lane & 15;
    const int g    = lane >> 4;

    __shared__ __align__(16) unsigned short wtT[C_HEAD * WSTR]; // W [o][c] bf16 padded, 16.9 KB
    __shared__ float lds_psum[C_HEAD][6];
    __shared__ float lds_pmax[C_HEAD][6];
    __shared__ float vp[3 * C_HEAD];
    __shared__ float base_l[CV], dco_l[CV], f5_l[CV];

    // ---- one-time: W as bf16 into LDS, same [o][c] layout (k-contiguous for B-frag) ----
    for (int i = tid; i < C_HEAD * C_IN; i += NTHR) {
        int o = i >> 8, c = i & 255;
        wtT[o * WSTR + c] = f2bf(conv_w[i]);
    }
    __syncthreads();

    f32x4 acc[4][2];
    #pragma unroll
    for (int mi = 0; mi < 4; ++mi)
        #pragma unroll
        for (int n = 0; n < 2; ++n)
            acc[mi][n] = (f32x4){0.f, 0.f, 0.f, 0.f};

    const float* __restrict__ xb = x + (size_t)b * C_IN * HW;

    // ---- main loop: NO barriers. A-fragments straight from global, B from LDS ----
    // A: lane -> row p = wave*64 + mi*16 + l15, k = t*32 + g*8 + e
    // B: lane -> k = t*32 + g*8 + e, col o = n*16 + l15
    #pragma unroll
    for (int t = 0; t < 8; ++t) {
        bf16x8 wf[2];
        #pragma unroll
        for (int n = 0; n < 2; ++n)
            wf[n] = *(const bf16x8*)&wtT[(n * 16 + l15) * WSTR + t * 32 + g * 8];

        bf16x8 a[4];
        #pragma unroll
        for (int mi = 0; mi < 4; ++mi) {
            int p = wave * 64 + mi * 16 + l15;
            if (p >= HW) p = HW - 1;                       // clamp; masked at reduction
            const float* xp = xb + (t * 32 + g * 8) * HW + p;
            float v[8];
            #pragma unroll
            for (int e = 0; e < 8; ++e) v[e] = xp[e * HW];
            bf16x8 f;
            #pragma unroll
            for (int e = 0; e < 8; ++e) f[e] = (short)f2bf(v[e]);
            a[mi] = f;
        }

        #pragma unroll
        for (int mi = 0; mi < 4; ++mi)
            #pragma unroll
            for (int n = 0; n < 2; ++n)
                acc[mi][n] = __builtin_amdgcn_mfma_f32_16x16x32_bf16(
                    a[mi], wf[n], acc[mi][n], 0, 0, 0);
    }

    // ---- reduce over positions: lane holds D[p = wave*64+mi*16+g*4+r][o = n*16+l15] ----
    float s[2]  = {0.f, 0.f};
    float mx[2] = {-3.0e38f, -3.0e38f};
    #pragma unroll
    for (int n = 0; n < 2; ++n) {
        #pragma unroll
        for (int mi = 0; mi < 4; ++mi) {
            #pragma unroll
            for (int r = 0; r < 4; ++r) {
                int pp = wave * 64 + mi * 16 + g * 4 + r;
                float v = acc[mi][n][r];
                if (pp < HW) { s[n] += v; mx[n] = fmaxf(mx[n], v); }
            }
        }
        s[n] += __shfl_xor(s[n], 16, 64);
        s[n] += __shfl_xor(s[n], 32, 64);
        mx[n] = fmaxf(mx[n], __shfl_xor(mx[n], 16, 64));
        mx[n] = fmaxf(mx[n], __shfl_xor(mx[n], 32, 64));
    }
    if (lane < 32) {
        lds_psum[lane][wave] = (lane < 16) ? s[0] : s[1];
        lds_pmax[lane][wave] = (lane < 16) ? mx[0] : mx[1];
    }
    __syncthreads();

    if (tid < C_HEAD) {
        float ss = 0.f, mm = -3.0e38f;
        #pragma unroll
        for (int w = 0; w < 6; ++w) { ss += lds_psum[tid][w]; mm = fmaxf(mm, lds_pmax[tid][w]); }
        float mean1 = ss * (1.0f / (float)HW);
        vp[tid]              = mean1;
        vp[C_HEAD + tid]     = mean1 * ((19.0f - 9.0f) * 0.1f);
        vp[2 * C_HEAD + tid] = mm;
    }
    __syncthreads();

    // ---- heads: wave 0 ----
    if (wave == 0) {
        const int j = lane;
        float h1 = 0.f, h3 = 0.f;
        if (j < CV) {
            float a1 = fc1_b[j], a3 = fc3_b[j], a4 = fc4_b[j];
            #pragma unroll
            for (int k = 0; k < 96; ++k) {
                float v = vp[k];
                a1 = fmaf(v, fc1_w[j * 96 + k], a1);
                a3 = fmaf(v, fc3_w[j * 96 + k], a3);
                a4 = fmaf(v, fc4_w[j * 97 + k], a4);
            }
            h1 = fmaxf(a1, 0.f) * fc2_w[j];
            h3 = fmaxf(a3, 0.f) * sc_w[j];
            base_l[j] = a4;
            dco_l[j]  = fc4_w[j * 97 + 96];
            f5_l[j]   = fc5_w[j];
        }
        float s1 = h1, s3 = h3;
        #pragma unroll
        for (int off = 32; off > 0; off >>= 1) {
            s1 += __shfl_xor(s1, off, 64);
            s3 += __shfl_xor(s3, off, 64);
        }
        float game = tanhf(s1 + fc2_b[0]);
        float scal = s3 + sc_b[0];
        if (lane == 0) out[b] = game;

        float z = -3.0e38f;
        if (lane < 41) {
            float dval = (float)(lane - 20);
            float lg = fc5_b[0];
            #pragma unroll
            for (int jj = 0; jj < CV; ++jj) {
                float t2 = fmaf(dval, dco_l[jj], base_l[jj]);
                t2 = fmaxf(t2, 0.f);
                lg = fmaf(t2, f5_l[jj], lg);
            }
            z = lg * scal;
        }
        float mz = z;
        #pragma unroll
        for (int off = 32; off > 0; off >>= 1) mz = fmaxf(mz, __shfl_xor(mz, off, 64));
        float e = (lane < 41) ? expf(z - mz) : 0.f;
        float se = e;
        #pragma unroll
        for (int off = 32; off > 0; off >>= 1) se += __shfl_xor(se, off, 64);
        if (lane < 41) out[B + b * 41 + lane] = e / se;
    }
}

extern "C" void kernel_launch(void* const* d_in, const int* in_sizes, int n_in,
                              void* d_out, int out_size, void* d_ws, size_t ws_size,
                              hipStream_t stream) {
    const float* x      = (const float*)d_in[0];
    const float* conv_w = (const float*)d_in[1];
    const float* fc1_w  = (const float*)d_in[2];
    const float* fc1_b  = (const float*)d_in[3];
    const float* fc2_w  = (const float*)d_in[4];
    const float* fc2_b  = (const float*)d_in[5];
    const float* fc3_w  = (const float*)d_in[6];
    const float* fc3_b  = (const float*)d_in[7];
    const float* sc_w   = (const float*)d_in[8];
    const float* sc_b   = (const float*)d_in[9];
    const float* fc4_w  = (const float*)d_in[10];
    const float* fc4_b  = (const float*)d_in[11];
    const float* fc5_w  = (const float*)d_in[12];
    const float* fc5_b  = (const float*)d_in[13];
    float* out = (float*)d_out;

    int B = in_sizes[0] / (C_IN * HW);

    vh_fused<<<dim3(B), dim3(NTHR), 0, stream>>>(
        x, conv_w, fc1_w, fc1_b, fc2_w, fc2_b, fc3_w, fc3_b,
        sc_w, sc_b, fc4_w, fc4_b, fc5_w, fc5_b, out, B);
}